// Round 6
// baseline (209.235 us; speedup 1.0000x reference)
//
#include <hip/hip_runtime.h>
#include <hip/hip_bf16.h>

// B=32, T=1024, D=256 fixed by the reference problem.
typedef __attribute__((ext_vector_type(8))) short bf16x8;
typedef __attribute__((ext_vector_type(4))) float f32x4;

#define INVT (1.0f/0.07f)

static __device__ __forceinline__ short f2bf(float f){
    unsigned int u = __float_as_uint(f);
    unsigned int r = (u + 0x7fffu + ((u >> 16) & 1u)) >> 16;
    return (short)r;
}
static __device__ __forceinline__ float bf2f(short s){
    return __uint_as_float(((unsigned int)(unsigned short)s) << 16);
}

// async global->LDS, 16B per lane; LDS dest = wave-uniform base + lane*16
static __device__ __forceinline__ void gld16(const void* g, void* l){
    __builtin_amdgcn_global_load_lds(
        (const __attribute__((address_space(1))) unsigned int*)g,
        (__attribute__((address_space(3))) unsigned int*)l, 16, 0, 0);
}

// ---- prep: blocks 0..511 convert W to bf16; blocks 512..543 per-batch rank scan + zero bsum
__global__ __launch_bounds__(256) void prep_kernel(const float* __restrict__ Weeg,
                                                   const float* __restrict__ Weye,
                                                   const int* __restrict__ mask,
                                                   short* __restrict__ Wout,
                                                   int* __restrict__ rank,
                                                   int* __restrict__ idx,
                                                   int* __restrict__ Tv,
                                                   float* __restrict__ cb,
                                                   float* __restrict__ bsum){
    __shared__ int ssum[256];
    int tid = threadIdx.x;
    if (blockIdx.x < 512){
        int i = blockIdx.x * 256 + tid;
        float v = (i < 65536) ? Weeg[i] : Weye[i - 65536];
        Wout[i] = f2bf(v);
        return;
    }
    int b = blockIdx.x - 512;
    if (tid == 0) bsum[b] = 0.f;
    int local[4]; int s = 0;
    #pragma unroll
    for (int q = 0; q < 4; ++q){
        int t = tid*4 + q;
        local[q] = (mask[b*1024 + t] > 0) ? 1 : 0;
        s += local[q];
    }
    ssum[tid] = s;
    __syncthreads();
    for (int off = 1; off < 256; off <<= 1){
        int add = (tid >= off) ? ssum[tid - off] : 0;
        __syncthreads();
        ssum[tid] += add;
        __syncthreads();
    }
    int run = ssum[tid] - s;
    #pragma unroll
    for (int q = 0; q < 4; ++q){
        int t = tid*4 + q;
        int g = b*1024 + t;
        run += local[q];
        rank[g] = run - 1;
        cb[g]   = local[q] ? 0.0f : -1e9f;
        if (local[q]) idx[b*1024 + run - 1] = t;
    }
    if (tid == 255) Tv[b] = ssum[255];
}

// ---- fused projection + L2 normalize, both modalities (blockIdx.y selects).
// W staged via global_load_lds(16B) into XOR-swizzled unpadded LDS (32 KB).
// 64 x-rows/block, 4 waves x 16 rows; 5 blocks/CU (LDS-capped).
__global__ __launch_bounds__(256, 5) void proj_kernel(const float* __restrict__ Aeeg,
                                                      const float* __restrict__ Aeye,
                                                      const short* __restrict__ Wbf,
                                                      short* __restrict__ Eout,
                                                      short* __restrict__ Vout){
    __shared__ short sW[64 * 256];     // unpadded; XOR-swizzled in 16B blocks
    int sel = blockIdx.y;
    const float* A   = sel ? Aeye : Aeeg;
    const short* W   = Wbf + sel * 65536;
    short*       Out = sel ? Vout : Eout;

    int tid = threadIdx.x;
    int w = tid >> 6, lane = tid & 63;
    int l15 = lane & 15, lq = lane >> 4;
    int kb  = lq * 8;
    int row0 = blockIdx.x * 64;

    // X-row fragments (B-operand), f32 -> bf16
    bf16x8 xf[8];
    {
        const float* ap = A + (size_t)(row0 + w*16 + l15) * 256 + kb;
        #pragma unroll
        for (int g = 0; g < 8; ++g){
            float4 x0 = *(const float4*)(ap + g*32);
            float4 x1 = *(const float4*)(ap + g*32 + 4);
            bf16x8 t;
            t[0]=f2bf(x0.x); t[1]=f2bf(x0.y); t[2]=f2bf(x0.z); t[3]=f2bf(x0.w);
            t[4]=f2bf(x1.x); t[5]=f2bf(x1.y); t[6]=f2bf(x1.z); t[7]=f2bf(x1.w);
            xf[g] = t;
        }
    }

    f32x4 acc[16];
    #pragma unroll
    for (int q = 0; q < 16; ++q) acc[q] = (f32x4){0.f,0.f,0.f,0.f};

    int ro   = lane >> 5;        // 0..1: row within a 1KB gld16 issue
    int cb_s = lane & 31;        // 16B col-block within a 512B row
    int s7   = l15 & 7;

    #pragma unroll
    for (int pass = 0; pass < 4; ++pass){
        if (pass) __syncthreads();
        // stage W rows [pass*64, +64): each wave 16 rows, 2 rows per issue
        #pragma unroll
        for (int p = 0; p < 8; ++p){
            int rl  = w*16 + p*2 + ro;                 // LDS row index
            int cbg = cb_s ^ ((p*2 + ro) & 7);         // swizzled global col-block
            gld16(W + (size_t)(pass*64 + rl)*256 + cbg*8,
                  &sW[(w*16 + p*2) * 256]);
        }
        __syncthreads();
        #pragma unroll
        for (int nt = 0; nt < 4; ++nt){
            f32x4 c = acc[pass*4 + nt];
            int rbase = (nt*16 + l15) * 256;
            #pragma unroll
            for (int g = 0; g < 8; ++g){
                bf16x8 wf = *(const bf16x8*)&sW[rbase + (((g*4 + lq) ^ s7) << 3)];
                c = __builtin_amdgcn_mfma_f32_16x16x32_bf16(wf, xf[g], c, 0, 0, 0);
            }
            acc[pass*4 + nt] = c;
        }
    }

    // D[e][xrow]: lane holds xrow = l15, e = (pass*4+nt)*16 + lq*4 + r
    float ss = 0.f;
    #pragma unroll
    for (int q = 0; q < 16; ++q){
        #pragma unroll
        for (int r = 0; r < 4; ++r){ float x = acc[q][r]; ss += x*x; }
    }
    ss += __shfl_xor(ss, 16);
    ss += __shfl_xor(ss, 32);
    float scale = 1.0f / fmaxf(sqrtf(ss), 1e-12f);

    short* op = Out + (size_t)(row0 + w*16 + l15) * 256 + lq*4;
    #pragma unroll
    for (int q = 0; q < 16; ++q){
        short4 pk;
        pk.x = f2bf(acc[q][0] * scale);
        pk.y = f2bf(acc[q][1] * scale);
        pk.z = f2bf(acc[q][2] * scale);
        pk.w = f2bf(acc[q][3] * scale);
        *(short4*)(op + ((q >> 2) * 64 + (q & 3) * 16)) = pk;
    }
}

// ---- loss: dual-LDS GEMM, 128x128 tile, 4 waves 2x2, each wave 64x64.
// K=256 in 4 chunks of 64 via global_load_lds(16B) into XOR-swizzled LDS.
// Epilogue: exp(s/T + cb) row-sums -> psum[b][i][slice] (16 slices per b).
// 5 blocks/CU (LDS-capped at 32 KB).
__global__ __launch_bounds__(256, 5) void loss_kernel(const short* __restrict__ E,
                                                      const short* __restrict__ V,
                                                      const float* __restrict__ cb,
                                                      float* __restrict__ psum){
    __shared__ short sE[128 * 64];     // unpadded; XOR-swizzled in 16B blocks
    __shared__ short sV[128 * 64];

    int i0 = blockIdx.x * 128;
    int j0 = blockIdx.y * 128;
    int b  = blockIdx.z;

    int tid = threadIdx.x;
    int w = tid >> 6, lane = tid & 63;
    int wi = w >> 1, wj = w & 1;
    int l15 = lane & 15, lq = lane >> 4;
    int s7 = l15 & 7;

    // staging: wave w stages rows [w*32, +32); 8 rows x 128B per issue.
    int swz = ((lane & 7) ^ (lane >> 3)) * 8;
    const short* Eg = E + ((size_t)b*1024 + i0 + w*32 + (lane>>3))*256 + swz;
    const short* Vg = V + ((size_t)b*1024 + j0 + w*32 + (lane>>3))*256 + swz;
    short* sEw = &sE[(w*32)*64];
    short* sVw = &sV[(w*32)*64];

    float cbv[4];
    #pragma unroll
    for (int jj = 0; jj < 4; ++jj)
        cbv[jj] = cb[b*1024 + j0 + wj*64 + jj*16 + l15];

    f32x4 acc[4][4];
    #pragma unroll
    for (int ii = 0; ii < 4; ++ii)
        #pragma unroll
        for (int jj = 0; jj < 4; ++jj) acc[ii][jj] = (f32x4){0.f,0.f,0.f,0.f};

    #pragma unroll
    for (int kc = 0; kc < 4; ++kc){
        __syncthreads();
        #pragma unroll
        for (int p = 0; p < 4; ++p){
            gld16(Eg + kc*64 + p*2048, sEw + p*512);
            gld16(Vg + kc*64 + p*2048, sVw + p*512);
        }
        __syncthreads();

        #pragma unroll
        for (int ks = 0; ks < 2; ++ks){
            bf16x8 af[4], bf[4];
            #pragma unroll
            for (int t = 0; t < 4; ++t){
                int co = (((ks*4 + lq) ^ s7)) << 3;
                af[t] = *(const bf16x8*)&sE[(wi*64 + t*16 + l15)*64 + co];
                bf[t] = *(const bf16x8*)&sV[(wj*64 + t*16 + l15)*64 + co];
            }
            #pragma unroll
            for (int ii = 0; ii < 4; ++ii)
                #pragma unroll
                for (int jj = 0; jj < 4; ++jj)
                    acc[ii][jj] = __builtin_amdgcn_mfma_f32_16x16x32_bf16(af[ii], bf[jj], acc[ii][jj], 0, 0, 0);
        }
    }

    // epilogue: ls[ii][r] = sum_jj exp(acc*INVT + cb[j])
    float ls[4][4];
    #pragma unroll
    for (int ii = 0; ii < 4; ++ii){
        #pragma unroll
        for (int r = 0; r < 4; ++r){
            float s = 0.f;
            #pragma unroll
            for (int jj = 0; jj < 4; ++jj)
                s += __expf(fmaf(acc[ii][jj][r], INVT, cbv[jj]));
            ls[ii][r] = s;
        }
    }
    #pragma unroll
    for (int ii = 0; ii < 4; ++ii){
        #pragma unroll
        for (int r = 0; r < 4; ++r){
            float v = ls[ii][r];
            v += __shfl_xor(v, 1);
            v += __shfl_xor(v, 2);
            v += __shfl_xor(v, 4);
            v += __shfl_xor(v, 8);
            ls[ii][r] = v;
        }
    }
    if (l15 == 0){
        int slice = blockIdx.y*2 + wj;
        int ibase = i0 + wi*64 + lq*4;
        float* pp = psum + (((size_t)b << 10) << 4);
        #pragma unroll
        for (int ii = 0; ii < 4; ++ii){
            #pragma unroll
            for (int r = 0; r < 4; ++r)
                pp[(size_t)(ibase + ii*16 + r)*16 + slice] = ls[ii][r];
        }
    }
}

// ---- banded positive max: one 16-lane group per row, <=5 candidate cols via idx.
__global__ __launch_bounds__(256) void pos_kernel(const short* __restrict__ E,
                                                  const short* __restrict__ V,
                                                  const int* __restrict__ mask,
                                                  const int* __restrict__ rank,
                                                  const int* __restrict__ idx,
                                                  const int* __restrict__ Tv,
                                                  float* __restrict__ pmax){
    int tid = threadIdx.x;
    int gl  = tid & 15;
    int rf  = (blockIdx.x * 256 + tid) >> 4;   // 0..32767
    int b   = rf >> 10;
    if (mask[rf] <= 0) return;

    int ri = rank[rf];
    int tv = Tv[b];
    int lo = ri - 2; if (lo < 0) lo = 0;
    int hi = ri + 2; if (hi > tv - 1) hi = tv - 1;

    const short* epp = E + (size_t)rf * 256 + gl * 16;
    float ev[16];
    {
        bf16x8 e0 = *(const bf16x8*)epp;
        bf16x8 e1 = *(const bf16x8*)(epp + 8);
        #pragma unroll
        for (int k = 0; k < 8; ++k){ ev[k] = bf2f(e0[k]); ev[8+k] = bf2f(e1[k]); }
    }
    float pm = -1e30f;
    for (int r = lo; r <= hi; ++r){
        int j = idx[b*1024 + r];
        const short* vpp = V + ((size_t)(b*1024) + j) * 256 + gl * 16;
        bf16x8 v0 = *(const bf16x8*)vpp;
        bf16x8 v1 = *(const bf16x8*)(vpp + 8);
        float s = 0.f;
        #pragma unroll
        for (int k = 0; k < 8; ++k){
            s = fmaf(ev[k],   bf2f(v0[k]), s);
            s = fmaf(ev[8+k], bf2f(v1[k]), s);
        }
        s += __shfl_xor(s, 1);
        s += __shfl_xor(s, 2);
        s += __shfl_xor(s, 4);
        s += __shfl_xor(s, 8);
        pm = fmaxf(pm, s);
    }
    if (gl == 0) pmax[rf] = pm * INVT;
}

// ---- partial reduce: 4 blocks per b, each thread one i; coalesced 64B psum reads.
// atomicAdd partial sums into bsum[b] (zeroed by prep).
__global__ __launch_bounds__(256) void reduce_kernel(const float* __restrict__ psum,
                                                     const float* __restrict__ pmax,
                                                     const int* __restrict__ mask,
                                                     float* __restrict__ bsum){
    int b  = blockIdx.x >> 2;
    int i  = (blockIdx.x & 3) * 256 + threadIdx.x;
    int g  = b*1024 + i;
    float a = 0.f;
    if (mask[g] > 0){
        const float* pp = psum + ((size_t)g << 4);
        float ps = 0.f;
        #pragma unroll
        for (int s = 0; s < 16; ++s) ps += pp[s];
        a = logf(ps) - pmax[g];
    }
    #pragma unroll
    for (int m = 1; m < 64; m <<= 1) a += __shfl_xor(a, m);
    if ((threadIdx.x & 63) == 0 && a != 0.f) atomicAdd(&bsum[b], a);
}

// ---- final: out = sum_b (Tv>=2 ? bsum/Tv : 0) / 32
__global__ void final_kernel(const float* __restrict__ bsum,
                             const int* __restrict__ Tv,
                             float* __restrict__ out){
    int tid = threadIdx.x;
    float v = 0.f;
    if (tid < 32){
        int tv = Tv[tid];
        if (tv >= 2) v = bsum[tid] / (float)tv;
    }
    #pragma unroll
    for (int m = 1; m < 64; m <<= 1) v += __shfl_xor(v, m);
    if (tid == 0) out[0] = v / 32.0f;
}

extern "C" void kernel_launch(void* const* d_in, const int* in_sizes, int n_in,
                              void* d_out, int out_size, void* d_ws, size_t ws_size,
                              hipStream_t stream) {
    const float* eeg  = (const float*)d_in[0];
    const float* eye  = (const float*)d_in[1];
    const int*   mask = (const int*)d_in[2];
    const float* Weeg = (const float*)d_in[3];
    const float* Weye = (const float*)d_in[4];
    float* out = (float*)d_out;

    char* ws = (char*)d_ws;
    short* e_bf  = (short*)(ws);                       // 16 MiB
    short* v_bf  = (short*)(ws + 16777216);            // 16 MiB
    short* wbf   = (short*)(ws + 33554432);            // 256 KiB
    int*   rank  = (int*)  (ws + 33816576);            // 128 KiB
    int*   idx   = (int*)  (ws + 33947648);            // 128 KiB
    float* cb    = (float*)(ws + 34078720);            // 128 KiB
    float* psum  = (float*)(ws + 34209792);            // 2 MiB (32 b x 1024 i x 16 slices)
    float* pmax  = (float*)(ws + 36306944);            // 128 KiB
    int*   Tv    = (int*)  (ws + 36438016);            // 128 B
    float* bsum  = (float*)(ws + 36438144);            // 128 B

    prep_kernel<<<544, 256, 0, stream>>>(Weeg, Weye, mask, wbf, rank, idx, Tv, cb, bsum);
    proj_kernel<<<dim3(512, 2), 256, 0, stream>>>(eeg, eye, wbf, e_bf, v_bf);
    loss_kernel<<<dim3(8, 8, 32), 256, 0, stream>>>(e_bf, v_bf, cb, psum);
    pos_kernel<<<2048, 256, 0, stream>>>(e_bf, v_bf, mask, rank, idx, Tv, pmax);
    reduce_kernel<<<128, 256, 0, stream>>>(psum, pmax, mask, bsum);
    final_kernel<<<1, 64, 0, stream>>>(bsum, Tv, out);
}

// Round 7
// 173.211 us; speedup vs baseline: 1.2080x; 1.2080x over previous
//
#include <hip/hip_runtime.h>
#include <hip/hip_bf16.h>

// B=32, T=1024, D=256 fixed by the reference problem.
typedef __attribute__((ext_vector_type(8))) short bf16x8;
typedef __attribute__((ext_vector_type(4))) float f32x4;

#define INVT (1.0f/0.07f)

static __device__ __forceinline__ short f2bf(float f){
    unsigned int u = __float_as_uint(f);
    unsigned int r = (u + 0x7fffu + ((u >> 16) & 1u)) >> 16;
    return (short)r;
}
static __device__ __forceinline__ float bf2f(short s){
    return __uint_as_float(((unsigned int)(unsigned short)s) << 16);
}

// async global->LDS, 16B per lane; LDS dest = wave-uniform base + lane*16
static __device__ __forceinline__ void gld16(const void* g, void* l){
    __builtin_amdgcn_global_load_lds(
        (const __attribute__((address_space(1))) unsigned int*)g,
        (__attribute__((address_space(3))) unsigned int*)l, 16, 0, 0);
}

// ---- prep: blocks 0..511 convert W to bf16; blocks 512..543 per-batch rank scan + zero bsum
__global__ __launch_bounds__(256) void prep_kernel(const float* __restrict__ Weeg,
                                                   const float* __restrict__ Weye,
                                                   const int* __restrict__ mask,
                                                   short* __restrict__ Wout,
                                                   int* __restrict__ rank,
                                                   int* __restrict__ idx,
                                                   int* __restrict__ Tv,
                                                   float* __restrict__ cb,
                                                   float* __restrict__ bsum){
    __shared__ int ssum[256];
    int tid = threadIdx.x;
    if (blockIdx.x < 512){
        int i = blockIdx.x * 256 + tid;
        float v = (i < 65536) ? Weeg[i] : Weye[i - 65536];
        Wout[i] = f2bf(v);
        return;
    }
    int b = blockIdx.x - 512;
    if (tid == 0) bsum[b] = 0.f;
    int local[4]; int s = 0;
    #pragma unroll
    for (int q = 0; q < 4; ++q){
        int t = tid*4 + q;
        local[q] = (mask[b*1024 + t] > 0) ? 1 : 0;
        s += local[q];
    }
    ssum[tid] = s;
    __syncthreads();
    for (int off = 1; off < 256; off <<= 1){
        int add = (tid >= off) ? ssum[tid - off] : 0;
        __syncthreads();
        ssum[tid] += add;
        __syncthreads();
    }
    int run = ssum[tid] - s;
    #pragma unroll
    for (int q = 0; q < 4; ++q){
        int t = tid*4 + q;
        int g = b*1024 + t;
        run += local[q];
        rank[g] = run - 1;
        cb[g]   = local[q] ? 0.0f : -1e9f;
        if (local[q]) idx[b*1024 + run - 1] = t;
    }
    if (tid == 255) Tv[b] = ssum[255];
}

// ---- fused projection + L2 normalize, both modalities (blockIdx.y selects).
// W staged via global_load_lds(16B) into XOR-swizzled unpadded LDS (32 KB).
// 64 x-rows/block, 4 waves x 16 rows; 5 blocks/CU (LDS-capped).
__global__ __launch_bounds__(256, 5) void proj_kernel(const float* __restrict__ Aeeg,
                                                      const float* __restrict__ Aeye,
                                                      const short* __restrict__ Wbf,
                                                      short* __restrict__ Eout,
                                                      short* __restrict__ Vout){
    __shared__ short sW[64 * 256];     // unpadded; XOR-swizzled in 16B blocks
    int sel = blockIdx.y;
    const float* A   = sel ? Aeye : Aeeg;
    const short* W   = Wbf + sel * 65536;
    short*       Out = sel ? Vout : Eout;

    int tid = threadIdx.x;
    int w = tid >> 6, lane = tid & 63;
    int l15 = lane & 15, lq = lane >> 4;
    int kb  = lq * 8;
    int row0 = blockIdx.x * 64;

    // X-row fragments (B-operand), f32 -> bf16
    bf16x8 xf[8];
    {
        const float* ap = A + (size_t)(row0 + w*16 + l15) * 256 + kb;
        #pragma unroll
        for (int g = 0; g < 8; ++g){
            float4 x0 = *(const float4*)(ap + g*32);
            float4 x1 = *(const float4*)(ap + g*32 + 4);
            bf16x8 t;
            t[0]=f2bf(x0.x); t[1]=f2bf(x0.y); t[2]=f2bf(x0.z); t[3]=f2bf(x0.w);
            t[4]=f2bf(x1.x); t[5]=f2bf(x1.y); t[6]=f2bf(x1.z); t[7]=f2bf(x1.w);
            xf[g] = t;
        }
    }

    f32x4 acc[16];
    #pragma unroll
    for (int q = 0; q < 16; ++q) acc[q] = (f32x4){0.f,0.f,0.f,0.f};

    int ro   = lane >> 5;        // 0..1: row within a 1KB gld16 issue
    int cb_s = lane & 31;        // 16B col-block within a 512B row
    int s7   = l15 & 7;

    #pragma unroll
    for (int pass = 0; pass < 4; ++pass){
        if (pass) __syncthreads();
        // stage W rows [pass*64, +64): each wave 16 rows, 2 rows per issue
        #pragma unroll
        for (int p = 0; p < 8; ++p){
            int rl  = w*16 + p*2 + ro;                 // LDS row index
            int cbg = cb_s ^ ((p*2 + ro) & 7);         // swizzled global col-block
            gld16(W + (size_t)(pass*64 + rl)*256 + cbg*8,
                  &sW[(w*16 + p*2) * 256]);
        }
        __syncthreads();
        #pragma unroll
        for (int nt = 0; nt < 4; ++nt){
            f32x4 c = acc[pass*4 + nt];
            int rbase = (nt*16 + l15) * 256;
            #pragma unroll
            for (int g = 0; g < 8; ++g){
                bf16x8 wf = *(const bf16x8*)&sW[rbase + (((g*4 + lq) ^ s7) << 3)];
                c = __builtin_amdgcn_mfma_f32_16x16x32_bf16(wf, xf[g], c, 0, 0, 0);
            }
            acc[pass*4 + nt] = c;
        }
    }

    // D[e][xrow]: lane holds xrow = l15, e = (pass*4+nt)*16 + lq*4 + r
    float ss = 0.f;
    #pragma unroll
    for (int q = 0; q < 16; ++q){
        #pragma unroll
        for (int r = 0; r < 4; ++r){ float x = acc[q][r]; ss += x*x; }
    }
    ss += __shfl_xor(ss, 16);
    ss += __shfl_xor(ss, 32);
    float scale = 1.0f / fmaxf(sqrtf(ss), 1e-12f);

    short* op = Out + (size_t)(row0 + w*16 + l15) * 256 + lq*4;
    #pragma unroll
    for (int q = 0; q < 16; ++q){
        short4 pk;
        pk.x = f2bf(acc[q][0] * scale);
        pk.y = f2bf(acc[q][1] * scale);
        pk.z = f2bf(acc[q][2] * scale);
        pk.w = f2bf(acc[q][3] * scale);
        *(short4*)(op + ((q >> 2) * 64 + (q & 3) * 16)) = pk;
    }
}

// ---- loss: dual-LDS GEMM, 128x128 tile, 4 waves 2x2, each wave 64x64.
// 1-D grid 2048, XCD-aware decode: all 64 blocks of batch b land on XCD b%8,
// consecutively -> b's 1MB E/V working set stays in that XCD's L2.
// K=256 in 4 chunks of 64 via global_load_lds(16B) into XOR-swizzled LDS.
// Epilogue: exp(s/T + cb) row-sums -> psum[b][slice][i], dense 64-lane stores.
__global__ __launch_bounds__(256, 5) void loss_kernel(const short* __restrict__ E,
                                                      const short* __restrict__ V,
                                                      const float* __restrict__ cb,
                                                      float* __restrict__ psum){
    __shared__ short sE[128 * 64];     // unpadded; XOR-swizzled in 16B blocks
    __shared__ short sV[128 * 64];

    // decode: xcd = n&7, m = n>>3; b = (m>>6)*8 + xcd; lm = m&63; ib = lm>>3, jb = lm&7
    int n  = blockIdx.x;
    int m  = n >> 3;
    int b  = ((m >> 6) << 3) | (n & 7);
    int lm = m & 63;
    int i0 = (lm >> 3) * 128;
    int jb = lm & 7;
    int j0 = jb * 128;

    int tid = threadIdx.x;
    int w = tid >> 6, lane = tid & 63;
    int wi = w >> 1, wj = w & 1;
    int l15 = lane & 15, lq = lane >> 4;
    int s7 = l15 & 7;

    // staging: wave w stages rows [w*32, +32); 8 rows x 128B per issue.
    int swz = ((lane & 7) ^ (lane >> 3)) * 8;
    const short* Eg = E + ((size_t)b*1024 + i0 + w*32 + (lane>>3))*256 + swz;
    const short* Vg = V + ((size_t)b*1024 + j0 + w*32 + (lane>>3))*256 + swz;
    short* sEw = &sE[(w*32)*64];
    short* sVw = &sV[(w*32)*64];

    float cbv[4];
    #pragma unroll
    for (int jj = 0; jj < 4; ++jj)
        cbv[jj] = cb[b*1024 + j0 + wj*64 + jj*16 + l15];

    f32x4 acc[4][4];
    #pragma unroll
    for (int ii = 0; ii < 4; ++ii)
        #pragma unroll
        for (int jj = 0; jj < 4; ++jj) acc[ii][jj] = (f32x4){0.f,0.f,0.f,0.f};

    #pragma unroll
    for (int kc = 0; kc < 4; ++kc){
        __syncthreads();
        #pragma unroll
        for (int p = 0; p < 4; ++p){
            gld16(Eg + kc*64 + p*2048, sEw + p*512);
            gld16(Vg + kc*64 + p*2048, sVw + p*512);
        }
        __syncthreads();

        #pragma unroll
        for (int ks = 0; ks < 2; ++ks){
            bf16x8 af[4], bf[4];
            #pragma unroll
            for (int t = 0; t < 4; ++t){
                int co = (((ks*4 + lq) ^ s7)) << 3;
                af[t] = *(const bf16x8*)&sE[(wi*64 + t*16 + l15)*64 + co];
                bf[t] = *(const bf16x8*)&sV[(wj*64 + t*16 + l15)*64 + co];
            }
            #pragma unroll
            for (int ii = 0; ii < 4; ++ii)
                #pragma unroll
                for (int jj = 0; jj < 4; ++jj)
                    acc[ii][jj] = __builtin_amdgcn_mfma_f32_16x16x32_bf16(af[ii], bf[jj], acc[ii][jj], 0, 0, 0);
        }
    }

    // epilogue: ls[ii][r] = sum_jj exp(acc*INVT + cb[j]), reduced over 16 lanes
    float ls[4][4];
    #pragma unroll
    for (int ii = 0; ii < 4; ++ii){
        #pragma unroll
        for (int r = 0; r < 4; ++r){
            float s = 0.f;
            #pragma unroll
            for (int jj = 0; jj < 4; ++jj)
                s += __expf(fmaf(acc[ii][jj][r], INVT, cbv[jj]));
            ls[ii][r] = s;
        }
    }
    #pragma unroll
    for (int ii = 0; ii < 4; ++ii){
        #pragma unroll
        for (int r = 0; r < 4; ++r){
            float v = ls[ii][r];
            v += __shfl_xor(v, 1);
            v += __shfl_xor(v, 2);
            v += __shfl_xor(v, 4);
            v += __shfl_xor(v, 8);
            ls[ii][r] = v;
        }
    }
    // lane-select: lane with l15==n takes ls[n>>2][n&3]; dense 64-lane store
    float myv = ls[0][0];
    #pragma unroll
    for (int q = 1; q < 16; ++q)
        if (l15 == q) myv = ls[q>>2][q&3];
    int slice = jb*2 + wj;
    float* pp = psum + (((size_t)(b*16 + slice)) << 10);
    pp[i0 + wi*64 + lq*4 + (l15>>2)*16 + (l15&3)] = myv;
}

// ---- banded positive max: one 16-lane group per row, <=5 candidate cols via idx.
__global__ __launch_bounds__(256) void pos_kernel(const short* __restrict__ E,
                                                  const short* __restrict__ V,
                                                  const int* __restrict__ mask,
                                                  const int* __restrict__ rank,
                                                  const int* __restrict__ idx,
                                                  const int* __restrict__ Tv,
                                                  float* __restrict__ pmax){
    int tid = threadIdx.x;
    int gl  = tid & 15;
    int rf  = (blockIdx.x * 256 + tid) >> 4;   // 0..32767
    int b   = rf >> 10;
    if (mask[rf] <= 0) return;

    int ri = rank[rf];
    int tv = Tv[b];
    int lo = ri - 2; if (lo < 0) lo = 0;
    int hi = ri + 2; if (hi > tv - 1) hi = tv - 1;

    const short* epp = E + (size_t)rf * 256 + gl * 16;
    float ev[16];
    {
        bf16x8 e0 = *(const bf16x8*)epp;
        bf16x8 e1 = *(const bf16x8*)(epp + 8);
        #pragma unroll
        for (int k = 0; k < 8; ++k){ ev[k] = bf2f(e0[k]); ev[8+k] = bf2f(e1[k]); }
    }
    float pm = -1e30f;
    for (int r = lo; r <= hi; ++r){
        int j = idx[b*1024 + r];
        const short* vpp = V + ((size_t)(b*1024) + j) * 256 + gl * 16;
        bf16x8 v0 = *(const bf16x8*)vpp;
        bf16x8 v1 = *(const bf16x8*)(vpp + 8);
        float s = 0.f;
        #pragma unroll
        for (int k = 0; k < 8; ++k){
            s = fmaf(ev[k],   bf2f(v0[k]), s);
            s = fmaf(ev[8+k], bf2f(v1[k]), s);
        }
        s += __shfl_xor(s, 1);
        s += __shfl_xor(s, 2);
        s += __shfl_xor(s, 4);
        s += __shfl_xor(s, 8);
        pm = fmaxf(pm, s);
    }
    if (gl == 0) pmax[rf] = pm * INVT;
}

// ---- partial reduce: 4 blocks per b, each thread one i; coalesced psum reads.
// atomicAdd partial sums into bsum[b] (zeroed by prep).
__global__ __launch_bounds__(256) void reduce_kernel(const float* __restrict__ psum,
                                                     const float* __restrict__ pmax,
                                                     const int* __restrict__ mask,
                                                     float* __restrict__ bsum){
    int b  = blockIdx.x >> 2;
    int i  = (blockIdx.x & 3) * 256 + threadIdx.x;
    int g  = b*1024 + i;
    float a = 0.f;
    if (mask[g] > 0){
        const float* pp = psum + ((size_t)b << 14);
        float ps = 0.f;
        #pragma unroll
        for (int s = 0; s < 16; ++s) ps += pp[i + (s << 10)];
        a = logf(ps) - pmax[g];
    }
    #pragma unroll
    for (int m = 1; m < 64; m <<= 1) a += __shfl_xor(a, m);
    if ((threadIdx.x & 63) == 0 && a != 0.f) atomicAdd(&bsum[b], a);
}

// ---- final: out = sum_b (Tv>=2 ? bsum/Tv : 0) / 32
__global__ void final_kernel(const float* __restrict__ bsum,
                             const int* __restrict__ Tv,
                             float* __restrict__ out){
    int tid = threadIdx.x;
    float v = 0.f;
    if (tid < 32){
        int tv = Tv[tid];
        if (tv >= 2) v = bsum[tid] / (float)tv;
    }
    #pragma unroll
    for (int m = 1; m < 64; m <<= 1) v += __shfl_xor(v, m);
    if (tid == 0) out[0] = v / 32.0f;
}

extern "C" void kernel_launch(void* const* d_in, const int* in_sizes, int n_in,
                              void* d_out, int out_size, void* d_ws, size_t ws_size,
                              hipStream_t stream) {
    const float* eeg  = (const float*)d_in[0];
    const float* eye  = (const float*)d_in[1];
    const int*   mask = (const int*)d_in[2];
    const float* Weeg = (const float*)d_in[3];
    const float* Weye = (const float*)d_in[4];
    float* out = (float*)d_out;

    char* ws = (char*)d_ws;
    short* e_bf  = (short*)(ws);                       // 16 MiB
    short* v_bf  = (short*)(ws + 16777216);            // 16 MiB
    short* wbf   = (short*)(ws + 33554432);            // 256 KiB
    int*   rank  = (int*)  (ws + 33816576);            // 128 KiB
    int*   idx   = (int*)  (ws + 33947648);            // 128 KiB
    float* cb    = (float*)(ws + 34078720);            // 128 KiB
    float* psum  = (float*)(ws + 34209792);            // 2 MiB (32 b x 16 slices x 1024 i)
    float* pmax  = (float*)(ws + 36306944);            // 128 KiB
    int*   Tv    = (int*)  (ws + 36438016);            // 128 B
    float* bsum  = (float*)(ws + 36438144);            // 128 B

    prep_kernel<<<544, 256, 0, stream>>>(Weeg, Weye, mask, wbf, rank, idx, Tv, cb, bsum);
    proj_kernel<<<dim3(512, 2), 256, 0, stream>>>(eeg, eye, wbf, e_bf, v_bf);
    loss_kernel<<<2048, 256, 0, stream>>>(e_bf, v_bf, cb, psum);
    pos_kernel<<<2048, 256, 0, stream>>>(e_bf, v_bf, mask, rank, idx, Tv, pmax);
    reduce_kernel<<<128, 256, 0, stream>>>(psum, pmax, mask, bsum);
    final_kernel<<<1, 64, 0, stream>>>(bsum, Tv, out);
}